// Round 1
// baseline (285.328 us; speedup 1.0000x reference)
//
#include <hip/hip_runtime.h>
#include <hip/hip_bf16.h>
#include <stdint.h>
#include <stddef.h>

using short8  = __attribute__((ext_vector_type(8))) short;
using short4v = __attribute__((ext_vector_type(4))) short;
using int4v   = __attribute__((ext_vector_type(4))) int;
using f32x4   = __attribute__((ext_vector_type(4))) float;
typedef __hip_bfloat16 bf16_t;

__device__ __forceinline__ void glds16(const void* g, const void* l) {
  __builtin_amdgcn_global_load_lds(
      (const __attribute__((address_space(1))) void*)g,
      (__attribute__((address_space(3))) void*)l, 16, 0, 0);
}
__device__ __forceinline__ short bfbits(float x) {
  bf16_t h = __float2bfloat16(x);
  return __builtin_bit_cast(short, h);
}
// pack two fp32 -> two bf16 (RTZ) in one v_perm_b32
__device__ __forceinline__ int pk2(float lo, float hi) {
  return __builtin_amdgcn_perm(__builtin_bit_cast(unsigned, hi),
                               __builtin_bit_cast(unsigned, lo), 0x07060302u);
}

// ---------------------------------------------------------------------------
// dtype probe: fp32 reinterpreted as bf16 shows huge/NaN values -> flag=1.
// ---------------------------------------------------------------------------
__global__ void dtype_probe(const unsigned short* __restrict__ w, int* flag) {
  __shared__ int sbad;
  const int tid = threadIdx.x;
  if (tid == 0) sbad = 0;
  __syncthreads();
  int bad = 0;
  for (int i = tid; i < 4096; i += 256) {
    float f = __uint_as_float((unsigned)w[i] << 16);
    if (!(fabsf(f) <= 1e10f)) bad = 1;
  }
  if (bad) sbad = 1;  // benign race: same value
  __syncthreads();
  if (tid == 0) *flag = sbad;
}

// ---------------------------------------------------------------------------
// Both weight transposes in one launch. bx<96: Wqkv[1024,3072]->WqkvT.
// bx>=96: Wout[1024,1024]->WoutT.  32x32 LDS tiles, coalesced both sides.
// ---------------------------------------------------------------------------
__global__ __launch_bounds__(256)
void transpose_both(const void* __restrict__ Wqkv, bf16_t* __restrict__ WqkvT,
                    const void* __restrict__ Wout, bf16_t* __restrict__ WoutT,
                    const int* __restrict__ flag) {
  __shared__ float tile[32][33];
  const int tx = threadIdx.x, ty = threadIdx.y;
  int bx = blockIdx.x;
  const void* Wv;
  bf16_t* Wt;
  int C;
  if (bx < 96) {
    Wv = Wqkv; Wt = WqkvT; C = 3072;
  } else {
    bx -= 96; Wv = Wout; Wt = WoutT; C = 1024;
  }
  const int n0 = bx * 32, k0 = blockIdx.y * 32;
  const int isf = *flag;
#pragma unroll
  for (int j = 0; j < 4; ++j) {
    const int k = k0 + ty + j * 8;
    tile[ty + j * 8][tx] =
        isf ? ((const float*)Wv)[(size_t)k * C + n0 + tx]
            : __bfloat162float(((const bf16_t*)Wv)[(size_t)k * C + n0 + tx]);
  }
  __syncthreads();
#pragma unroll
  for (int j = 0; j < 4; ++j) {
    const int n = n0 + ty + j * 8;
    Wt[(size_t)n * 1024 + k0 + tx] = __float2bfloat16(tile[tx][ty + j * 8]);
  }
}

// ---------------------------------------------------------------------------
// X (fp32 or bf16 per flag) -> bf16, 4 elems/thread.
// ---------------------------------------------------------------------------
__global__ __launch_bounds__(256)
void convert_x(const void* __restrict__ Xv, bf16_t* __restrict__ Xb, int total,
               const int* __restrict__ flag) {
  const int i = (blockIdx.x * 256 + threadIdx.x) * 4;
  if (i >= total) return;
  if (*flag) {
    const float4 v = *(const float4*)((const float*)Xv + i);
    Xb[i + 0] = __float2bfloat16(v.x);
    Xb[i + 1] = __float2bfloat16(v.y);
    Xb[i + 2] = __float2bfloat16(v.z);
    Xb[i + 3] = __float2bfloat16(v.w);
  } else {
    *(uint2*)(Xb + i) = *(const uint2*)((const bf16_t*)Xv + i);
  }
}

// ---------------------------------------------------------------------------
// C[M,N] = A[M,K] * Bt[N,K]^T + bias.   256x256 tile, BK=64, 8 waves (2Mx4N),
// 8-phase/2-tile schedule: per phase {ds_read subtile || stage 1 half-tile ->
// raw s_barrier -> setprio(1) 16 MFMA setprio(0) -> raw s_barrier}; counted
// s_waitcnt vmcnt(2) once per K-tile (never 0).  LDS = ring of 8 x 16KB
// half-tile slots (A-lo,A-hi,B-lo,B-hi x dbuf) = 128 KB, staged 5 halves
// ahead.  XOR (row&7) 16B-chunk swizzle on global source; linear glds16 dest;
// same XOR on ds_read (T2).  MODE 0: store C.  MODE 1: scatter to Q (pre-
// scaled by CSC), K, V^T bf16.
// ---------------------------------------------------------------------------
template <int MODE>
__global__ __launch_bounds__(512, 2)
void gemm_k(const bf16_t* __restrict__ A, const bf16_t* __restrict__ Bt,
            const void* __restrict__ biasv, void* __restrict__ Cv,
            bf16_t* __restrict__ Qo, bf16_t* __restrict__ Ko,
            bf16_t* __restrict__ Vo, int M, int N, int K,
            const int* __restrict__ flag) {
  constexpr float CSC = 0.18033688011112042f;  // (1/sqrt(64)) * log2(e)
  __shared__ __align__(16) bf16_t lds[8 * 8192];  // 8 slots x 16 KB = 128 KB

  const int isf32 = *flag;
  const int tid  = threadIdx.x;
  const int w    = tid >> 6;
  const int lane = tid & 63;
  const int lrow = lane & 15;
  const int quad = lane >> 4;
  const int wr   = w >> 2;   // 0..1 : M half (128 rows)
  const int wc   = w & 3;    // 0..3 : N quarter (64 cols)
  const int m0 = blockIdx.x * 256;
  const int n0 = blockIdx.y * 256;
  const int fk  = lrow & 7;
  const int sl0 = ((0 + quad) ^ fk) << 4;  // ks=0 chunk byte offset
  const int sl1 = ((4 + quad) ^ fk) << 4;  // ks=1
  const int NT = K >> 6;

  f32x4 acc[8][4];
#pragma unroll
  for (int i = 0; i < 8; ++i)
#pragma unroll
    for (int j = 0; j < 4; ++j)
#pragma unroll
      for (int r = 0; r < 4; ++r) acc[i][j][r] = 0.f;

  // stage half-tile n: n = 4*tile + {0:A rows 0-127, 1:A rows 128-255,
  // 2:B rows 0-127, 3:B rows 128-255}; slot = n&7 (ring = double buffer).
  auto stage = [&](int n) {
    if (n >= 4 * NT) return;
    const int slot = n & 7;
    const int part = n & 3;
    const int kt   = (n >> 2) << 6;
    const bf16_t* src = (part < 2) ? A : Bt;
    const int rb = ((part < 2) ? m0 : n0) + ((part & 1) << 7);
#pragma unroll
    for (int i = 0; i < 2; ++i) {
      const int cbase = i * 512 + w * 64;  // wave-uniform LDS base
      const int c = cbase + lane;
      const int row = c >> 3, ch = c & 7;
      glds16(src + (size_t)(rb + row) * K + kt + ((ch ^ (row & 7)) << 3),
             (const char*)lds + slot * 16384 + cbase * 16);
    }
  };

  const char* ldsc = (const char*)lds;
  // per-wave constant LDS offsets (tile-parity qb added per tile)
  const int aoff = (wr << 14) + (lrow << 7);
  const int boff = ((2 + (wc >> 1)) << 14) + ((((wc & 1) << 6) + lrow) << 7);

  // prologue: tile0 {A0,A1,B0,B1} + tile1 A0; leave last half in flight.
#pragma unroll
  for (int n = 0; n < 5; ++n) stage(n);
  asm volatile("s_waitcnt vmcnt(2)" ::: "memory");
  __builtin_amdgcn_s_barrier();

  for (int t = 0; t < NT; ++t) {
    const int qb = (t & 1) << 16;  // buffer parity: 4 slots = 64 KB

    // -- P1: read a[0-3]ks0 + b[*]ks0 ; stage t+1.A1 ; MFMA (mi0-3, ks0)
    short8 al[4], b0[4];
#pragma unroll
    for (int mi = 0; mi < 4; ++mi)
      al[mi] = *(const short8*)(ldsc + qb + aoff + mi * 2048 + sl0);
#pragma unroll
    for (int ni = 0; ni < 4; ++ni)
      b0[ni] = *(const short8*)(ldsc + qb + boff + ni * 2048 + sl0);
    stage(4 * t + 5);
    __builtin_amdgcn_s_barrier();
    __builtin_amdgcn_s_setprio(1);
#pragma unroll
    for (int mi = 0; mi < 4; ++mi)
#pragma unroll
      for (int ni = 0; ni < 4; ++ni)
        acc[mi][ni] = __builtin_amdgcn_mfma_f32_16x16x32_bf16(
            al[mi], b0[ni], acc[mi][ni], 0, 0, 0);
    __builtin_amdgcn_s_setprio(0);
    __builtin_amdgcn_s_barrier();

    // -- P2: read a[4-7]ks0 + b[*]ks1 ; stage t+1.B0 ; MFMA (mi4-7, ks0)
    short8 ah[4], b1[4];
#pragma unroll
    for (int mi = 0; mi < 4; ++mi)
      ah[mi] = *(const short8*)(ldsc + qb + aoff + (mi + 4) * 2048 + sl0);
#pragma unroll
    for (int ni = 0; ni < 4; ++ni)
      b1[ni] = *(const short8*)(ldsc + qb + boff + ni * 2048 + sl1);
    stage(4 * t + 6);
    __builtin_amdgcn_s_barrier();
    __builtin_amdgcn_s_setprio(1);
#pragma unroll
    for (int mi = 0; mi < 4; ++mi)
#pragma unroll
      for (int ni = 0; ni < 4; ++ni)
        acc[mi + 4][ni] = __builtin_amdgcn_mfma_f32_16x16x32_bf16(
            ah[mi], b0[ni], acc[mi + 4][ni], 0, 0, 0);
    __builtin_amdgcn_s_setprio(0);
    __builtin_amdgcn_s_barrier();

    // -- P3: read a[0-3]ks1 + a[4-7]ks1 ; stage t+1.B1 ; MFMA (mi0-3, ks1)
    short8 al1[4], ah1[4];
#pragma unroll
    for (int mi = 0; mi < 4; ++mi)
      al1[mi] = *(const short8*)(ldsc + qb + aoff + mi * 2048 + sl1);
#pragma unroll
    for (int mi = 0; mi < 4; ++mi)
      ah1[mi] = *(const short8*)(ldsc + qb + aoff + (mi + 4) * 2048 + sl1);
    stage(4 * t + 7);
    __builtin_amdgcn_s_barrier();
    __builtin_amdgcn_s_setprio(1);
#pragma unroll
    for (int mi = 0; mi < 4; ++mi)
#pragma unroll
      for (int ni = 0; ni < 4; ++ni)
        acc[mi][ni] = __builtin_amdgcn_mfma_f32_16x16x32_bf16(
            al1[mi], b1[ni], acc[mi][ni], 0, 0, 0);
    __builtin_amdgcn_s_setprio(0);
    // drain our ds_reads: next phase's stage overwrites this tile's A0 slot
    asm volatile("s_waitcnt lgkmcnt(0)" ::: "memory");
    __builtin_amdgcn_s_barrier();

    // -- P4: stage t+2.A0 ; counted vmcnt (tile t+1 complete, 1 half in
    //        flight) ; MFMA (mi4-7, ks1)
    stage(4 * t + 8);
    asm volatile("s_waitcnt vmcnt(2)" ::: "memory");
    __builtin_amdgcn_s_barrier();
    __builtin_amdgcn_s_setprio(1);
#pragma unroll
    for (int mi = 0; mi < 4; ++mi)
#pragma unroll
      for (int ni = 0; ni < 4; ++ni)
        acc[mi + 4][ni] = __builtin_amdgcn_mfma_f32_16x16x32_bf16(
            ah1[mi], b1[ni], acc[mi + 4][ni], 0, 0, 0);
    __builtin_amdgcn_s_setprio(0);
    __builtin_amdgcn_s_barrier();
  }

  // epilogue: C/D layout col=lane&15, row=quad*4+reg
  if (MODE == 1) {
    const int sec = n0 >> 10;          // block-uniform (256 | 1024)
    const int b = m0 >> 11;            // block-uniform (256 | 2048)
    const int s0 = (m0 & 2047) + wr * 128 + quad * 4;
#pragma unroll
    for (int mi = 0; mi < 8; ++mi) {
      const int s = s0 + mi * 16;
#pragma unroll
      for (int ni = 0; ni < 4; ++ni) {
        const int col = n0 + wc * 64 + ni * 16 + lrow;
        const float bv = isf32 ? ((const float*)biasv)[col]
                               : __bfloat162float(((const bf16_t*)biasv)[col]);
        const int h = (col >> 6) & 15, d = col & 63;
        if (sec == 2) {  // V^T[bh][d][s]: 4 consecutive s -> one 8B store
          short4v hv4;
#pragma unroll
          for (int r = 0; r < 4; ++r) hv4[r] = bfbits(acc[mi][ni][r] + bv);
          *(short4v*)(Vo + ((((size_t)b * 16 + h) * 64) + d) * 2048 + s) = hv4;
        } else if (sec == 0) {  // Q, pre-scaled by CSC
          bf16_t* dst = Qo + ((((size_t)b * 16 + h) * 2048) + s) * 64 + d;
#pragma unroll
          for (int r = 0; r < 4; ++r)
            dst[(size_t)r * 64] = __float2bfloat16((acc[mi][ni][r] + bv) * CSC);
        } else {
          bf16_t* dst = Ko + ((((size_t)b * 16 + h) * 2048) + s) * 64 + d;
#pragma unroll
          for (int r = 0; r < 4; ++r)
            dst[(size_t)r * 64] = __float2bfloat16(acc[mi][ni][r] + bv);
        }
      }
    }
  } else {
#pragma unroll
    for (int mi = 0; mi < 8; ++mi) {
#pragma unroll
      for (int ni = 0; ni < 4; ++ni) {
        const int col = n0 + wc * 64 + ni * 16 + lrow;
        const float bv = isf32 ? ((const float*)biasv)[col]
                               : __bfloat162float(((const bf16_t*)biasv)[col]);
#pragma unroll
        for (int r = 0; r < 4; ++r) {
          const int row = m0 + wr * 128 + mi * 16 + quad * 4 + r;
          const float val = acc[mi][ni][r] + bv;
          if (isf32)
            ((float*)Cv)[(size_t)row * N + col] = val;
          else
            ((bf16_t*)Cv)[(size_t)row * N + col] = __float2bfloat16(val);
        }
      }
    }
  }
}

// ---------------------------------------------------------------------------
// Flash attention: transposed-score + x32-PV + glds16 double-buffer.
// Q pre-scaled by CSC upstream -> p = exp2(s) directly (fixed-max softmax;
// scale cancels in 1/sum). Sum-of-p via MFMA ones-row. Staging is async
// global->LDS (no VGPRs, no ds_writes); one barrier per 64-key chunk.
// ---------------------------------------------------------------------------
__global__ __launch_bounds__(256, 3)
void attn_fwd(const bf16_t* __restrict__ Q, const bf16_t* __restrict__ K,
              const bf16_t* __restrict__ Vt, bf16_t* __restrict__ AO) {
  __shared__ __align__(16) bf16_t lK[2][64 * 64];  // [key][d], fk(row) swizzle
  __shared__ __align__(16) bf16_t lV[2][64 * 64];  // [d][key], row&7 swizzle

  const int tid  = threadIdx.x;
  const int w    = tid >> 6;
  const int lane = tid & 63;
  const int lrow = lane & 15;
  const int quad = lane >> 4;
  const int id = blockIdx.x;
  const int bh = (id & 7) * 8 + (id >> 7);       // XCD swizzle
  const int q0 = ((id >> 3) & 15) * 128;

  const bf16_t* Qb = Q + (size_t)bh * 2048 * 64;
  const bf16_t* Kb = K + (size_t)bh * 2048 * 64;
  const bf16_t* Vb = Vt + (size_t)bh * 64 * 2048;

  // per-lane constants for permuted K-frag reads
  const int rbase = (lrow >> 2) * 8 + (lrow & 3);
  const int fkl   = 2 * (lrow >> 2) + (lrow & 1);

  // Q fragments (B-operand): lane holds Q[q=lrow][d=ks*32+quad*8+j]
  short8 aq[2][2];
#pragma unroll
  for (int qt = 0; qt < 2; ++qt)
#pragma unroll
    for (int ks = 0; ks < 2; ++ks)
      aq[qt][ks] = *(const short8*)(Qb +
          (size_t)(q0 + w * 32 + qt * 16 + lrow) * 64 + ks * 32 + quad * 8);

  short8 ones;
#pragma unroll
  for (int j = 0; j < 8; ++j) ones[j] = (short)0x3F80;  // bf16 1.0

  f32x4 ot[4][2];   // O^T[d-tile][q-tile]: d=quad*4+r, q=lrow
  f32x4 lsacc[2];   // sum-of-p per q (replicated over quads)
#pragma unroll
  for (int dt = 0; dt < 4; ++dt)
    for (int qt = 0; qt < 2; ++qt)
      for (int r = 0; r < 4; ++r) ot[dt][qt][r] = 0.f;
  for (int qt = 0; qt < 2; ++qt)
    for (int r = 0; r < 4; ++r) lsacc[qt][r] = 0.f;

  // async staging: global source carries the XOR swizzle; LDS is lane-linear
  auto stage = [&](int buf, int kt) {
#pragma unroll
    for (int i = 0; i < 2; ++i) {
      const int cbase = i * 256 + w * 64;
      const int c = cbase + lane;
      const int row = c >> 3, ch = c & 7;
      const int fk = 2 * ((row >> 3) & 3) + (row & 1);
      glds16(Kb + (size_t)(kt + row) * 64 + (ch ^ fk) * 8,
             (const char*)lK[buf] + cbase * 16);
      glds16(Vb + (size_t)row * 2048 + kt + (ch ^ (row & 7)) * 8,
             (const char*)lV[buf] + cbase * 16);
    }
  };

  auto compute = [&](const bf16_t* lKb, const bf16_t* lVb) {
    f32x4 sc[2][2][2];  // [g][T][qt]
#pragma unroll
    for (int g = 0; g < 2; ++g)
      for (int T = 0; T < 2; ++T)
        for (int qt = 0; qt < 2; ++qt)
          for (int r = 0; r < 4; ++r) sc[g][T][qt][r] = 0.f;
#pragma unroll
    for (int ks = 0; ks < 2; ++ks) {
      short8 ak[2][2];
#pragma unroll
      for (int g = 0; g < 2; ++g)
#pragma unroll
        for (int T = 0; T < 2; ++T) {
          const int row = g * 32 + T * 4 + rbase;
          const int slot = (ks * 4 + quad) ^ fkl;
          ak[g][T] =
              *(const short8*)((const char*)lKb + row * 128 + slot * 16);
        }
#pragma unroll
      for (int g = 0; g < 2; ++g)
#pragma unroll
        for (int T = 0; T < 2; ++T)
#pragma unroll
          for (int qt = 0; qt < 2; ++qt)
            sc[g][T][qt] = __builtin_amdgcn_mfma_f32_16x16x32_bf16(
                ak[g][T], aq[qt][ks], sc[g][T][qt], 0, 0, 0);
    }
#pragma unroll
    for (int g = 0; g < 2; ++g) {
      short8 pb[2];
#pragma unroll
      for (int qt = 0; qt < 2; ++qt) {
        float p[8];
#pragma unroll
        for (int T = 0; T < 2; ++T)
#pragma unroll
          for (int r = 0; r < 4; ++r)
            p[T * 4 + r] = __builtin_amdgcn_exp2f(sc[g][T][qt][r]);
        int4v pi = {pk2(p[0], p[1]), pk2(p[2], p[3]), pk2(p[4], p[5]),
                    pk2(p[6], p[7])};
        pb[qt] = __builtin_bit_cast(short8, pi);
        lsacc[qt] = __builtin_amdgcn_mfma_f32_16x16x32_bf16(ones, pb[qt],
                                                            lsacc[qt], 0, 0, 0);
      }
#pragma unroll
      for (int dt = 0; dt < 4; ++dt) {
        const int row = dt * 16 + lrow;
        const int slot = (g * 4 + quad) ^ (row & 7);
        const short8 vf =
            *(const short8*)((const char*)lVb + row * 128 + slot * 16);
#pragma unroll
        for (int qt = 0; qt < 2; ++qt)
          ot[dt][qt] = __builtin_amdgcn_mfma_f32_16x16x32_bf16(
              vf, pb[qt], ot[dt][qt], 0, 0, 0);
      }
    }
  };

  stage(0, 0);
  __syncthreads();  // drains vmcnt: buf0 ready

  for (int kt = 0; kt < 2048; kt += 128) {
    if (kt + 64 < 2048) stage(1, kt + 64);   // in flight during compute
    compute(lK[0], lV[0]);
    __syncthreads();                          // buf1 ready; buf0 readers done
    if (kt + 128 < 2048) stage(0, kt + 128);
    compute(lK[1], lV[1]);
    __syncthreads();
  }

  // scale + store O^T -> AO[b*2048+s][h*64+d]
  const int b = bh >> 4, h = bh & 15;
#pragma unroll
  for (int qt = 0; qt < 2; ++qt) {
    const float inv = 1.f / lsacc[qt][0];
    const int srow = q0 + w * 32 + qt * 16 + lrow;
#pragma unroll
    for (int dt = 0; dt < 4; ++dt) {
      uint2 pack;
      short* ps = (short*)&pack;
#pragma unroll
      for (int r = 0; r < 4; ++r) ps[r] = bfbits(ot[dt][qt][r] * inv);
      *(uint2*)(AO + ((size_t)b * 2048 + srow) * 1024 + h * 64 + dt * 16 +
                quad * 4) = pack;
    }
  }
}

// ---------------------------------------------------------------------------
extern "C" void kernel_launch(void* const* d_in, const int* in_sizes, int n_in,
                              void* d_out, int out_size, void* d_ws,
                              size_t ws_size, hipStream_t stream) {
  const void* X    = d_in[0];
  const void* Wqkv = d_in[1];
  const void* bqkv = d_in[2];
  const void* Wout = d_in[3];
  const void* bout = d_in[4];

  char* ws = (char*)d_ws;
  bf16_t* WqkvT = (bf16_t*)(ws);               // [3072,1024]  6 MB
  bf16_t* WoutT = (bf16_t*)(ws + 6291456);     // [1024,1024]  2 MB
  bf16_t* Qw    = (bf16_t*)(ws + 8388608);     // [64,2048,64] 16 MB
  bf16_t* Kw    = (bf16_t*)(ws + 25165824);    // [64,2048,64] 16 MB
  bf16_t* Vw    = (bf16_t*)(ws + 41943040);    // [64,64,2048] 16 MB (V^T)
  bf16_t* AOw   = (bf16_t*)(ws + 58720256);    // [8192,1024]  16 MB
  bf16_t* Xbf   = AOw;  // aliases AOw: Xbf dead before attn writes AOw
  int*    flag  = (int*)(ws + 75497472);

  dtype_probe<<<1, 256, 0, stream>>>((const unsigned short*)Wqkv, flag);
  transpose_both<<<dim3(128, 32), dim3(32, 8), 0, stream>>>(Wqkv, WqkvT, Wout,
                                                            WoutT, flag);
  convert_x<<<8192, 256, 0, stream>>>(X, Xbf, 8388608, flag);

  gemm_k<1><<<dim3(32, 12), 512, 0, stream>>>(Xbf, WqkvT, bqkv, nullptr, Qw,
                                              Kw, Vw, 8192, 3072, 1024, flag);
  attn_fwd<<<1024, 256, 0, stream>>>(Qw, Kw, Vw, AOw);
  gemm_k<0><<<dim3(32, 4), 512, 0, stream>>>(AOw, WoutT, bout, d_out, nullptr,
                                             nullptr, nullptr, 8192, 1024, 1024,
                                             flag);
}

// Round 3
// 255.910 us; speedup vs baseline: 1.1150x; 1.1150x over previous
//
#include <hip/hip_runtime.h>
#include <hip/hip_bf16.h>
#include <stdint.h>
#include <stddef.h>

using short8  = __attribute__((ext_vector_type(8))) short;
using short4v = __attribute__((ext_vector_type(4))) short;
using int4v   = __attribute__((ext_vector_type(4))) int;
using f32x4   = __attribute__((ext_vector_type(4))) float;
typedef __hip_bfloat16 bf16_t;

__device__ __forceinline__ void glds16(const void* g, const void* l) {
  __builtin_amdgcn_global_load_lds(
      (const __attribute__((address_space(1))) void*)g,
      (__attribute__((address_space(3))) void*)l, 16, 0, 0);
}
__device__ __forceinline__ short bfbits(float x) {
  bf16_t h = __float2bfloat16(x);
  return __builtin_bit_cast(short, h);
}
// pack two fp32 -> two bf16 (RTZ) in one v_perm_b32
__device__ __forceinline__ int pk2(float lo, float hi) {
  return __builtin_amdgcn_perm(__builtin_bit_cast(unsigned, hi),
                               __builtin_bit_cast(unsigned, lo), 0x07060302u);
}

// ---------------------------------------------------------------------------
// Fused preprocessing: every block self-probes Wqkv dtype (fp32 reinterpreted
// as bf16 shows huge/NaN low-half words; 1024 samples -> P(miss) ~ 1e-26),
// so no separate probe kernel / flag dependency. Block 0 publishes the flag
// for the downstream GEMMs (stream-ordered). bid<4096: 32x32 transpose tiles
// (bx<96: Wqkv[1024,3072]->WqkvT; else Wout->WoutT). bid>=4096: X->bf16.
// ---------------------------------------------------------------------------
__global__ __launch_bounds__(256)
void preprocess(const void* __restrict__ Wqkv, bf16_t* __restrict__ WqkvT,
                const void* __restrict__ Wout, bf16_t* __restrict__ WoutT,
                const void* __restrict__ Xv, bf16_t* __restrict__ Xb,
                int* __restrict__ flag) {
  __shared__ int sbad;
  __shared__ float tile[32][33];
  const int tid = threadIdx.x;
  const int bid = blockIdx.x;
  if (tid == 0) sbad = 0;
  __syncthreads();
  {
    int bad = 0;
    const unsigned short* wp = (const unsigned short*)Wqkv;
#pragma unroll
    for (int j = 0; j < 4; ++j) {
      float f = __uint_as_float((unsigned)wp[tid + j * 256] << 16);
      if (!(fabsf(f) <= 1e10f)) bad = 1;
    }
    if (bad) sbad = 1;  // benign race: same value
  }
  __syncthreads();
  const int isf = sbad;
  if (bid == 0 && tid == 0) *flag = isf;

  if (bid < 4096) {
    int bx = bid & 127;
    const int by = bid >> 7;
    const int tx = tid & 31, ty = tid >> 5;
    const void* Wv;
    bf16_t* Wt;
    int C;
    if (bx < 96) {
      Wv = Wqkv; Wt = WqkvT; C = 3072;
    } else {
      bx -= 96; Wv = Wout; Wt = WoutT; C = 1024;
    }
    const int n0 = bx * 32, k0 = by * 32;
#pragma unroll
    for (int j = 0; j < 4; ++j) {
      const int k = k0 + ty + j * 8;
      tile[ty + j * 8][tx] =
          isf ? ((const float*)Wv)[(size_t)k * C + n0 + tx]
              : __bfloat162float(((const bf16_t*)Wv)[(size_t)k * C + n0 + tx]);
    }
    __syncthreads();
#pragma unroll
    for (int j = 0; j < 4; ++j) {
      const int n = n0 + ty + j * 8;
      Wt[(size_t)n * 1024 + k0 + tx] = __float2bfloat16(tile[tx][ty + j * 8]);
    }
  } else {
    const int i = ((bid - 4096) * 256 + tid) * 4;
    if (isf) {
      const float4 v = *(const float4*)((const float*)Xv + i);
      Xb[i + 0] = __float2bfloat16(v.x);
      Xb[i + 1] = __float2bfloat16(v.y);
      Xb[i + 2] = __float2bfloat16(v.z);
      Xb[i + 3] = __float2bfloat16(v.w);
    } else {
      *(uint2*)(Xb + i) = *(const uint2*)((const bf16_t*)Xv + i);
    }
  }
}

// ---------------------------------------------------------------------------
// C[M,N] = A[M,K] * Bt[N,K]^T + bias.  A,Bt bf16; bias/C dtype per flag.
// 128x128 tile, 4 waves, glds16 staging, XOR-swizzled LDS (proven m97-style).
// MODE 0: store C.  MODE 1: scatter to Q (pre-scaled by CSC), K, V^T bf16.
// ---------------------------------------------------------------------------
template <int MODE>
__global__ __launch_bounds__(256)
void gemm_k(const bf16_t* __restrict__ A, const bf16_t* __restrict__ Bt,
            const void* __restrict__ biasv, void* __restrict__ Cv,
            bf16_t* __restrict__ Qo, bf16_t* __restrict__ Ko,
            bf16_t* __restrict__ Vo, int M, int N, int K,
            const int* __restrict__ flag) {
  constexpr float CSC = 0.18033688011112042f;  // (1/sqrt(64)) * log2(e)
  __shared__ __align__(16) bf16_t lA[128 * 64];
  __shared__ __align__(16) bf16_t lB[128 * 64];

  const int isf32 = *flag;
  const int tid  = threadIdx.x;
  const int w    = tid >> 6;
  const int lane = tid & 63;
  const int lrow = lane & 15;
  const int quad = lane >> 4;
  const int m0 = blockIdx.x * 128;
  const int n0 = blockIdx.y * 128;
  const int wm = (w >> 1) * 64;
  const int wn = (w & 1) * 64;

  f32x4 acc[4][4];
  for (int i = 0; i < 4; ++i)
    for (int j = 0; j < 4; ++j)
      for (int r = 0; r < 4; ++r) acc[i][j][r] = 0.f;

  for (int kt = 0; kt < K; kt += 64) {
#pragma unroll
    for (int i = 0; i < 4; ++i) {
      const int cbase = i * 256 + w * 64;
      const int c = cbase + lane;
      const int row = c >> 3;
      const int q = (c & 7) ^ (row & 7);
      glds16(A + (size_t)(m0 + row) * K + kt + q * 8,
             (const char*)lA + cbase * 16);
      glds16(Bt + (size_t)(n0 + row) * K + kt + q * 8,
             (const char*)lB + cbase * 16);
    }
    __syncthreads();
#pragma unroll
    for (int ks = 0; ks < 2; ++ks) {
      short8 af[4], bfr[4];
#pragma unroll
      for (int mi = 0; mi < 4; ++mi) {
        const int row = wm + mi * 16 + lrow;
        const int slot = (ks * 4 + quad) ^ (row & 7);
        af[mi] = *(const short8*)((const char*)lA + row * 128 + slot * 16);
      }
#pragma unroll
      for (int ni = 0; ni < 4; ++ni) {
        const int row = wn + ni * 16 + lrow;
        const int slot = (ks * 4 + quad) ^ (row & 7);
        bfr[ni] = *(const short8*)((const char*)lB + row * 128 + slot * 16);
      }
#pragma unroll
      for (int mi = 0; mi < 4; ++mi)
#pragma unroll
        for (int ni = 0; ni < 4; ++ni)
          acc[mi][ni] = __builtin_amdgcn_mfma_f32_16x16x32_bf16(
              af[mi], bfr[ni], acc[mi][ni], 0, 0, 0);
    }
    __syncthreads();
  }

  // epilogue: C/D layout col=lane&15, row=quad*4+reg
  if (MODE == 1) {
    const int sec = n0 >> 10;          // block-uniform
    const int b = m0 >> 11;            // block-uniform
    const int s0 = (m0 & 2047) + wm + quad * 4;
#pragma unroll
    for (int mi = 0; mi < 4; ++mi) {
#pragma unroll
      for (int ni = 0; ni < 4; ++ni) {
        const int col = n0 + wn + ni * 16 + lrow;
        const float bv = isf32 ? ((const float*)biasv)[col]
                               : __bfloat162float(((const bf16_t*)biasv)[col]);
        const int h = (col >> 6) & 15, d = col & 63;
        const int s = s0 + mi * 16;
        if (sec == 2) {  // V^T[bh][d][s]: 4 consecutive s -> one 8B store
          short4v hv4;
#pragma unroll
          for (int r = 0; r < 4; ++r) hv4[r] = bfbits(acc[mi][ni][r] + bv);
          *(short4v*)(Vo + ((((size_t)b * 16 + h) * 64) + d) * 2048 + s) = hv4;
        } else if (sec == 0) {  // Q, pre-scaled by CSC
          bf16_t* dst = Qo + ((((size_t)b * 16 + h) * 2048) + s) * 64 + d;
#pragma unroll
          for (int r = 0; r < 4; ++r)
            dst[(size_t)r * 64] = __float2bfloat16((acc[mi][ni][r] + bv) * CSC);
        } else {
          bf16_t* dst = Ko + ((((size_t)b * 16 + h) * 2048) + s) * 64 + d;
#pragma unroll
          for (int r = 0; r < 4; ++r)
            dst[(size_t)r * 64] = __float2bfloat16(acc[mi][ni][r] + bv);
        }
      }
    }
  } else {
#pragma unroll
    for (int mi = 0; mi < 4; ++mi) {
#pragma unroll
      for (int ni = 0; ni < 4; ++ni) {
        const int col = n0 + wn + ni * 16 + lrow;
        const float bv = isf32 ? ((const float*)biasv)[col]
                               : __bfloat162float(((const bf16_t*)biasv)[col]);
#pragma unroll
        for (int r = 0; r < 4; ++r) {
          const int row = m0 + wm + mi * 16 + quad * 4 + r;
          const float val = acc[mi][ni][r] + bv;
          if (isf32)
            ((float*)Cv)[(size_t)row * N + col] = val;
          else
            ((bf16_t*)Cv)[(size_t)row * N + col] = __float2bfloat16(val);
        }
      }
    }
  }
}

// ---------------------------------------------------------------------------
// Flash attention: transposed-score + x32-PV + glds16 double-buffer.
// qt=4 widening: each wave owns 64 q-rows, so every K-frag and V-frag LDS
// read feeds 4 MFMA instead of 2 (72 MFMA / 16 ds_read_b128 per 64-key
// chunk; the r1 profile showed the qt=2 version LDS-issue-bound).
// Grid 512 = exactly 2 blocks/CU. Q pre-scaled by CSC -> p = exp2(s).
// Sum-of-p via MFMA ones-row. Async global->LDS staging, swizzled source.
// ---------------------------------------------------------------------------
__global__ __launch_bounds__(256, 2)
void attn_fwd(const bf16_t* __restrict__ Q, const bf16_t* __restrict__ K,
              const bf16_t* __restrict__ Vt, bf16_t* __restrict__ AO) {
  __shared__ __align__(16) bf16_t lK[2][64 * 64];  // [key][d], fk(row) swizzle
  __shared__ __align__(16) bf16_t lV[2][64 * 64];  // [d][key], row&7 swizzle

  const int tid  = threadIdx.x;
  const int w    = tid >> 6;
  const int lane = tid & 63;
  const int lrow = lane & 15;
  const int quad = lane >> 4;
  const int id = blockIdx.x;
  const int swz = (id & 7) * 64 + (id >> 3);  // XCD-contiguous bh chunks
  const int bh  = swz >> 3;
  const int q0  = (swz & 7) * 256;

  const bf16_t* Qb = Q + (size_t)bh * 2048 * 64;
  const bf16_t* Kb = K + (size_t)bh * 2048 * 64;
  const bf16_t* Vb = Vt + (size_t)bh * 64 * 2048;

  // per-lane constants for permuted K-frag reads
  const int rbase = (lrow >> 2) * 8 + (lrow & 3);
  const int fkl   = 2 * (lrow >> 2) + (lrow & 1);

  // Q fragments (B-operand): lane holds Q[q=lrow][d=ks*32+quad*8+j]
  short8 aq[4][2];
#pragma unroll
  for (int qt = 0; qt < 4; ++qt)
#pragma unroll
    for (int ks = 0; ks < 2; ++ks)
      aq[qt][ks] = *(const short8*)(Qb +
          (size_t)(q0 + w * 64 + qt * 16 + lrow) * 64 + ks * 32 + quad * 8);

  short8 ones;
#pragma unroll
  for (int j = 0; j < 8; ++j) ones[j] = (short)0x3F80;  // bf16 1.0

  f32x4 ot[4][4];   // O^T[d-tile][q-tile]: d=quad*4+r, q=lrow
  f32x4 lsacc[4];   // sum-of-p per q (replicated over quads)
#pragma unroll
  for (int dt = 0; dt < 4; ++dt)
#pragma unroll
    for (int qt = 0; qt < 4; ++qt)
#pragma unroll
      for (int r = 0; r < 4; ++r) ot[dt][qt][r] = 0.f;
#pragma unroll
  for (int qt = 0; qt < 4; ++qt)
#pragma unroll
    for (int r = 0; r < 4; ++r) lsacc[qt][r] = 0.f;

  // async staging: global source carries the XOR swizzle; LDS is lane-linear
  auto stage = [&](int buf, int kt) {
#pragma unroll
    for (int i = 0; i < 2; ++i) {
      const int cbase = i * 256 + w * 64;
      const int c = cbase + lane;
      const int row = c >> 3, ch = c & 7;
      const int fk = 2 * ((row >> 3) & 3) + (row & 1);
      glds16(Kb + (size_t)(kt + row) * 64 + (ch ^ fk) * 8,
             (const char*)lK[buf] + cbase * 16);
      glds16(Vb + (size_t)row * 2048 + kt + (ch ^ (row & 7)) * 8,
             (const char*)lV[buf] + cbase * 16);
    }
  };

  auto compute = [&](const bf16_t* lKb, const bf16_t* lVb) {
#pragma unroll
    for (int g = 0; g < 2; ++g) {
      f32x4 sc[2][4];  // [T][qt], keys g*32+T*16(permuted) x q
#pragma unroll
      for (int T = 0; T < 2; ++T)
#pragma unroll
        for (int qt = 0; qt < 4; ++qt)
#pragma unroll
          for (int r = 0; r < 4; ++r) sc[T][qt][r] = 0.f;
#pragma unroll
      for (int ks = 0; ks < 2; ++ks) {
        short8 ak[2];
#pragma unroll
        for (int T = 0; T < 2; ++T) {
          const int row = g * 32 + T * 4 + rbase;
          const int slot = (ks * 4 + quad) ^ fkl;
          ak[T] = *(const short8*)((const char*)lKb + row * 128 + slot * 16);
        }
#pragma unroll
        for (int T = 0; T < 2; ++T)
#pragma unroll
          for (int qt = 0; qt < 4; ++qt)
            sc[T][qt] = __builtin_amdgcn_mfma_f32_16x16x32_bf16(
                ak[T], aq[qt][ks], sc[T][qt], 0, 0, 0);
      }
      short8 pb[4];
#pragma unroll
      for (int qt = 0; qt < 4; ++qt) {
        float p[8];
#pragma unroll
        for (int T = 0; T < 2; ++T)
#pragma unroll
          for (int r = 0; r < 4; ++r)
            p[T * 4 + r] = __builtin_amdgcn_exp2f(sc[T][qt][r]);
        int4v pi = {pk2(p[0], p[1]), pk2(p[2], p[3]), pk2(p[4], p[5]),
                    pk2(p[6], p[7])};
        pb[qt] = __builtin_bit_cast(short8, pi);
        lsacc[qt] = __builtin_amdgcn_mfma_f32_16x16x32_bf16(ones, pb[qt],
                                                            lsacc[qt], 0, 0, 0);
      }
#pragma unroll
      for (int dt = 0; dt < 4; ++dt) {
        const int row = dt * 16 + lrow;
        const int slot = (g * 4 + quad) ^ (row & 7);
        const short8 vf =
            *(const short8*)((const char*)lVb + row * 128 + slot * 16);
#pragma unroll
        for (int qt = 0; qt < 4; ++qt)
          ot[dt][qt] = __builtin_amdgcn_mfma_f32_16x16x32_bf16(
              vf, pb[qt], ot[dt][qt], 0, 0, 0);
      }
    }
  };

  stage(0, 0);
  __syncthreads();  // drains vmcnt: buf0 ready

  for (int kt = 0; kt < 2048; kt += 128) {
    if (kt + 64 < 2048) stage(1, kt + 64);   // in flight during compute
    compute(lK[0], lV[0]);
    __syncthreads();                          // buf1 ready; buf0 readers done
    if (kt + 128 < 2048) stage(0, kt + 128);
    compute(lK[1], lV[1]);
    __syncthreads();
  }

  // scale + store O^T -> AO[b*2048+s][h*64+d]
  const int b = bh >> 4, h = bh & 15;
#pragma unroll
  for (int qt = 0; qt < 4; ++qt) {
    const float inv = 1.f / lsacc[qt][0];
    const int srow = q0 + w * 64 + qt * 16 + lrow;
#pragma unroll
    for (int dt = 0; dt < 4; ++dt) {
      uint2 pack;
      short* ps = (short*)&pack;
#pragma unroll
      for (int r = 0; r < 4; ++r) ps[r] = bfbits(ot[dt][qt][r] * inv);
      *(uint2*)(AO + ((size_t)b * 2048 + srow) * 1024 + h * 64 + dt * 16 +
                quad * 4) = pack;
    }
  }
}

// ---------------------------------------------------------------------------
extern "C" void kernel_launch(void* const* d_in, const int* in_sizes, int n_in,
                              void* d_out, int out_size, void* d_ws,
                              size_t ws_size, hipStream_t stream) {
  const void* X    = d_in[0];
  const void* Wqkv = d_in[1];
  const void* bqkv = d_in[2];
  const void* Wout = d_in[3];
  const void* bout = d_in[4];

  char* ws = (char*)d_ws;
  bf16_t* WqkvT = (bf16_t*)(ws);               // [3072,1024]  6 MB
  bf16_t* WoutT = (bf16_t*)(ws + 6291456);     // [1024,1024]  2 MB
  bf16_t* Qw    = (bf16_t*)(ws + 8388608);     // [64,2048,64] 16 MB
  bf16_t* Kw    = (bf16_t*)(ws + 25165824);    // [64,2048,64] 16 MB
  bf16_t* Vw    = (bf16_t*)(ws + 41943040);    // [64,64,2048] 16 MB (V^T)
  bf16_t* AOw   = (bf16_t*)(ws + 58720256);    // [8192,1024]  16 MB
  bf16_t* Xbf   = AOw;  // aliases AOw: Xbf dead before attn writes AOw
  int*    flag  = (int*)(ws + 75497472);

  preprocess<<<12288, 256, 0, stream>>>(Wqkv, WqkvT, Wout, WoutT, X, Xbf, flag);

  gemm_k<1><<<dim3(64, 24), 256, 0, stream>>>(Xbf, WqkvT, bqkv, nullptr, Qw,
                                              Kw, Vw, 8192, 3072, 1024, flag);
  attn_fwd<<<512, 256, 0, stream>>>(Qw, Kw, Vw, AOw);
  gemm_k<0><<<dim3(64, 8), 256, 0, stream>>>(AOw, WoutT, bout, d_out, nullptr,
                                             nullptr, nullptr, 8192, 1024, 1024,
                                             flag);
}